// Round 6
// baseline (215.839 us; speedup 1.0000x reference)
//
#include <hip/hip_runtime.h>

// ConsecutiveLoss: x is (4096, 8192) fp32.
// real_length[i] = nnz(row i); per_row = sum_{pos=1}^{rl-1} |x[i,pos]-x[i,pos-1]| / rl
// out = sum_{i>=1} per_row[i] / bsz
typedef float f4 __attribute__((ext_vector_type(4)));

constexpr int SEQ    = 8192;
constexpr int BSZ    = 4096;
constexpr int BLOCK  = 256;
constexpr int CHUNKS = SEQ / 4 / BLOCK;  // 8 float4 per thread
constexpr int NWAVE  = BLOCK / 64;

__global__ __launch_bounds__(BLOCK) void consec_loss_kernel(
    const float* __restrict__ x, float* __restrict__ ws,
    int* __restrict__ counter, float* __restrict__ out) {
    const int tid = threadIdx.x;
    const int row = blockIdx.x;
    const int wave = tid >> 6, lane = tid & 63;

    __shared__ float bnd[NWAVE][CHUNKS];  // each wave's lane-63 v[k].w
    __shared__ int   cred[NWAVE];
    __shared__ float sred[NWAVE];

    if (row == 0) {
        // Row 0 is skipped by the reference; this block is the finisher.
        if (tid == 0) {
            ws[0] = 0.0f;
            // wait for all 4095 worker blocks (counter memset to 0 each call)
            while (__hip_atomic_load(counter, __ATOMIC_RELAXED,
                                     __HIP_MEMORY_SCOPE_AGENT) < BSZ - 1)
                __builtin_amdgcn_s_sleep(8);
        }
        __syncthreads();
        __threadfence();                  // acquire: workers' ws stores now visible
        const f4* w4 = reinterpret_cast<const f4*>(ws);
        float s = 0.0f;
        #pragma unroll
        for (int k = 0; k < BSZ / 4 / BLOCK; ++k) {  // 4 float4 per thread
            f4 f = w4[tid + k * BLOCK];
            s += (f.x + f.y) + (f.z + f.w);
        }
        #pragma unroll
        for (int off = 32; off > 0; off >>= 1) s += __shfl_down(s, off, 64);
        if (lane == 0) sred[wave] = s;
        __syncthreads();
        if (tid == 0) out[0] = sred[0] + sred[1] + sred[2] + sred[3];
        return;
    }

    const f4* x4 = reinterpret_cast<const f4*>(x) + (size_t)row * (SEQ / 4);

    // ---- phase 1: issue ALL loads first (max MLP), non-temporal (zero reuse) ----
    f4 v[CHUNKS];
    #pragma unroll
    for (int k = 0; k < CHUNKS; ++k)
        v[k] = __builtin_nontemporal_load(x4 + tid + k * BLOCK);

    // ---- phase 2: speculative unmasked diffs + running min|x| (zero detection) ----
    float s  = 0.0f;
    float mn = 1.0f;                      // ==0 iff this lane saw a zero element
    #pragma unroll
    for (int k = 0; k < CHUNKS; ++k) {
        if (lane == 63) bnd[wave][k] = v[k].w;   // wave-boundary carry
        mn = fminf(mn, fminf(fminf(fabsf(v[k].x), fabsf(v[k].y)),
                             fminf(fabsf(v[k].z), fabsf(v[k].w))));
        const float prev = __shfl_up(v[k].w, 1, 64);
        if (lane > 0) s += fabsf(v[k].x - prev); // lanes 1..63 carry in-wave
        s += fabsf(v[k].y - v[k].x);
        s += fabsf(v[k].z - v[k].y);
        s += fabsf(v[k].w - v[k].z);
    }
    if (lane == 0) cred[wave] = __any(mn == 0.0f) ? 1 : 0;
    __syncthreads();
    const bool anyz = (cred[0] | cred[1] | cred[2] | cred[3]) != 0;

    float inv_div;
    if (!anyz) {
        // dense row (always, for Gaussian data): count == SEQ; speculative sum is
        // exact except the wave-boundary diffs only lane 0 couldn't compute.
        if (lane == 0) {
            #pragma unroll
            for (int k = 0; k < CHUNKS; ++k) {
                if (wave > 0)   s += fabsf(v[k].x - bnd[wave - 1][k]);
                else if (k > 0) s += fabsf(v[k].x - bnd[NWAVE - 1][k - 1]);
                // wave 0, chunk 0: position 0 has no predecessor
            }
        }
        inv_div = 1.0f / ((float)SEQ * (float)BSZ);
    } else {
        // slow path (row contains zeros): exact count + masked recompute, all
        // from register-resident v[]. Never taken on the bench data but correct.
        __syncthreads();                  // cred reads above must complete before rewrite
        int cnt = 0;
        #pragma unroll
        for (int k = 0; k < CHUNKS; ++k) {
            cnt += (v[k].x != 0.0f) + (v[k].y != 0.0f)
                 + (v[k].z != 0.0f) + (v[k].w != 0.0f);
        }
        #pragma unroll
        for (int off = 32; off > 0; off >>= 1) cnt += __shfl_down(cnt, off, 64);
        if (lane == 0) cred[wave] = cnt;
        __syncthreads();
        const int count = cred[0] + cred[1] + cred[2] + cred[3];

        s = 0.0f;
        #pragma unroll
        for (int k = 0; k < CHUNKS; ++k) {
            const int p0 = 4 * (tid + k * BLOCK);
            float prev = __shfl_up(v[k].w, 1, 64);
            if (lane == 0)
                prev = (wave > 0) ? bnd[wave - 1][k]
                                  : (k > 0 ? bnd[NWAVE - 1][k - 1] : 0.0f);
            if (p0 >= 1 && p0     < count) s += fabsf(v[k].x - prev);
            if (p0 + 1 < count)            s += fabsf(v[k].y - v[k].x);
            if (p0 + 2 < count)            s += fabsf(v[k].z - v[k].y);
            if (p0 + 3 < count)            s += fabsf(v[k].w - v[k].z);
        }
        inv_div = 1.0f / ((float)count * (float)BSZ);
    }

    #pragma unroll
    for (int off = 32; off > 0; off >>= 1) s += __shfl_down(s, off, 64);
    if (lane == 0) sred[wave] = s;
    __syncthreads();
    if (tid == 0) {
        const float tot = sred[0] + sred[1] + sred[2] + sred[3];
        ws[row] = tot * inv_div;
        __threadfence();                  // release: ws[row] visible before signal
        atomicAdd(counter, 1);            // device-scope by default
    }
}

extern "C" void kernel_launch(void* const* d_in, const int* in_sizes, int n_in,
                              void* d_out, int out_size, void* d_ws, size_t ws_size,
                              hipStream_t stream) {
    const float* x = (const float*)d_in[0];
    float* ws  = (float*)d_ws;            // [0..4095] per-row partials
    int* counter = (int*)(ws + BSZ);      // ws[4096]: completion counter
    float* out = (float*)d_out;
    // counter must start at 0 every call (poison leaves 0xAA; workers leave 4095)
    hipMemsetAsync(counter, 0, sizeof(int), stream);
    consec_loss_kernel<<<dim3(BSZ), dim3(BLOCK), 0, stream>>>(x, ws, counter, out);
}

// Round 7
// 67.445 us; speedup vs baseline: 3.2002x; 3.2002x over previous
//
#include <hip/hip_runtime.h>

// ConsecutiveLoss: x is (4096, 8192) fp32.
// real_length[i] = nnz(row i); per_row = sum_{pos=1}^{rl-1} |x[i,pos]-x[i,pos-1]| / rl
// out = sum_{i>=1} per_row[i] / bsz
typedef float f4 __attribute__((ext_vector_type(4)));

constexpr int SEQ    = 8192;
constexpr int BSZ    = 4096;
constexpr int BLOCK  = 256;
constexpr int CHUNKS = SEQ / 4 / BLOCK;  // 8 float4 per thread
constexpr int NWAVE  = BLOCK / 64;

__global__ __launch_bounds__(BLOCK) void consec_loss_kernel(
    const float* __restrict__ x, float* __restrict__ out) {
    const int tid = threadIdx.x;
    const int row = blockIdx.x;

    if (row == 0) return;                // row 0 is skipped by the reference

    const f4* x4 = reinterpret_cast<const f4*>(x) + (size_t)row * (SEQ / 4);
    const int wave = tid >> 6, lane = tid & 63;

    __shared__ float bnd[NWAVE][CHUNKS];  // each wave's lane-63 v[k].w
    __shared__ int   cred[NWAVE];
    __shared__ float sred[NWAVE];

    // ---- phase 1: issue ALL loads first (max MLP), non-temporal (zero reuse) ----
    f4 v[CHUNKS];
    #pragma unroll
    for (int k = 0; k < CHUNKS; ++k)
        v[k] = __builtin_nontemporal_load(x4 + tid + k * BLOCK);

    // ---- phase 2: speculative unmasked diffs + running min|x| (zero detection) ----
    float s  = 0.0f;
    float mn = 1.0f;                      // ==0 iff this lane saw a zero element
    #pragma unroll
    for (int k = 0; k < CHUNKS; ++k) {
        if (lane == 63) bnd[wave][k] = v[k].w;   // wave-boundary carry
        mn = fminf(mn, fminf(fminf(fabsf(v[k].x), fabsf(v[k].y)),
                             fminf(fabsf(v[k].z), fabsf(v[k].w))));
        const float prev = __shfl_up(v[k].w, 1, 64);
        if (lane > 0) s += fabsf(v[k].x - prev); // lanes 1..63 carry in-wave
        s += fabsf(v[k].y - v[k].x);
        s += fabsf(v[k].z - v[k].y);
        s += fabsf(v[k].w - v[k].z);
    }
    if (lane == 0) cred[wave] = __any(mn == 0.0f) ? 1 : 0;
    __syncthreads();
    const bool anyz = (cred[0] | cred[1] | cred[2] | cred[3]) != 0;

    float inv_div;
    if (!anyz) {
        // dense row (always, for Gaussian data): count == SEQ; speculative sum is
        // exact except the wave-boundary diffs only lane 0 couldn't compute.
        if (lane == 0) {
            #pragma unroll
            for (int k = 0; k < CHUNKS; ++k) {
                if (wave > 0)   s += fabsf(v[k].x - bnd[wave - 1][k]);
                else if (k > 0) s += fabsf(v[k].x - bnd[NWAVE - 1][k - 1]);
                // wave 0, chunk 0: position 0 has no predecessor
            }
        }
        inv_div = 1.0f / ((float)SEQ * (float)BSZ);
    } else {
        // slow path (row contains zeros): exact count + masked recompute, all
        // from register-resident v[]. Never taken on the bench data but correct.
        __syncthreads();                  // cred reads above must complete before rewrite
        int cnt = 0;
        #pragma unroll
        for (int k = 0; k < CHUNKS; ++k) {
            cnt += (v[k].x != 0.0f) + (v[k].y != 0.0f)
                 + (v[k].z != 0.0f) + (v[k].w != 0.0f);
        }
        #pragma unroll
        for (int off = 32; off > 0; off >>= 1) cnt += __shfl_down(cnt, off, 64);
        if (lane == 0) cred[wave] = cnt;
        __syncthreads();
        const int count = cred[0] + cred[1] + cred[2] + cred[3];

        s = 0.0f;
        #pragma unroll
        for (int k = 0; k < CHUNKS; ++k) {
            const int p0 = 4 * (tid + k * BLOCK);
            float prev = __shfl_up(v[k].w, 1, 64);
            if (lane == 0)
                prev = (wave > 0) ? bnd[wave - 1][k]
                                  : (k > 0 ? bnd[NWAVE - 1][k - 1] : 0.0f);
            if (p0 >= 1 && p0     < count) s += fabsf(v[k].x - prev);
            if (p0 + 1 < count)            s += fabsf(v[k].y - v[k].x);
            if (p0 + 2 < count)            s += fabsf(v[k].z - v[k].y);
            if (p0 + 3 < count)            s += fabsf(v[k].w - v[k].z);
        }
        inv_div = 1.0f / ((float)count * (float)BSZ);
    }

    #pragma unroll
    for (int off = 32; off > 0; off >>= 1) s += __shfl_down(s, off, 64);
    if (lane == 0) sred[wave] = s;
    __syncthreads();
    if (tid == 0) {
        const float tot = sred[0] + sred[1] + sred[2] + sred[3];
        // One same-address atomic per block; no fence needed (atomicAdd is
        // device-scope; no other memory ordering is required by the consumer).
        atomicAdd(out, tot * inv_div);
    }
}

extern "C" void kernel_launch(void* const* d_in, const int* in_sizes, int n_in,
                              void* d_out, int out_size, void* d_ws, size_t ws_size,
                              hipStream_t stream) {
    const float* x = (const float*)d_in[0];
    float* out = (float*)d_out;
    // out is poisoned once before timing and never restored between replays:
    // zero it every call, then accumulate into it.
    hipMemsetAsync(out, 0, sizeof(float), stream);
    consec_loss_kernel<<<dim3(BSZ), dim3(BLOCK), 0, stream>>>(x, out);
}

// Round 8
// 26.728 us; speedup vs baseline: 8.0754x; 2.5234x over previous
//
#include <hip/hip_runtime.h>

// ConsecutiveLoss: x is (4096, 8192) fp32.
// real_length[i] = nnz(row i); per_row = sum_{pos=1}^{rl-1} |x[i,pos]-x[i,pos-1]| / rl
// out = sum_{i>=1} per_row[i] / bsz
typedef float f4 __attribute__((ext_vector_type(4)));

constexpr int SEQ    = 8192;
constexpr int BSZ    = 4096;
constexpr int BLOCK  = 256;
constexpr int CHUNKS = SEQ / 4 / BLOCK;  // 8 float4 per thread
constexpr int NWAVE  = BLOCK / 64;

__global__ __launch_bounds__(BLOCK) void consec_loss_kernel(
    const float* __restrict__ x, float* __restrict__ ws) {
    const int tid = threadIdx.x;
    const int row = blockIdx.x;

    if (row == 0) {                      // row 0 is skipped by the reference
        if (tid == 0) ws[0] = 0.0f;
        return;
    }

    const f4* x4 = reinterpret_cast<const f4*>(x) + (size_t)row * (SEQ / 4);
    const int wave = tid >> 6, lane = tid & 63;

    __shared__ float bnd[NWAVE][CHUNKS];  // each wave's lane-63 v[k].w
    __shared__ int   cred[NWAVE];
    __shared__ float sred[NWAVE];

    // ---- phase 1: issue ALL loads first (max MLP). PLAIN loads (no nt):
    // the 128 MiB input fits the 256 MiB Infinity Cache, so retained lines
    // serve subsequent graph replays from L3 instead of HBM.
    f4 v[CHUNKS];
    #pragma unroll
    for (int k = 0; k < CHUNKS; ++k)
        v[k] = x4[tid + k * BLOCK];

    // ---- phase 2: speculative unmasked diffs + running min|x| (zero detection) ----
    float s  = 0.0f;
    float mn = 1.0f;                      // ==0 iff this lane saw a zero element
    #pragma unroll
    for (int k = 0; k < CHUNKS; ++k) {
        if (lane == 63) bnd[wave][k] = v[k].w;   // wave-boundary carry
        mn = fminf(mn, fminf(fminf(fabsf(v[k].x), fabsf(v[k].y)),
                             fminf(fabsf(v[k].z), fabsf(v[k].w))));
        const float prev = __shfl_up(v[k].w, 1, 64);
        if (lane > 0) s += fabsf(v[k].x - prev); // lanes 1..63 carry in-wave
        s += fabsf(v[k].y - v[k].x);
        s += fabsf(v[k].z - v[k].y);
        s += fabsf(v[k].w - v[k].z);
    }
    if (lane == 0) cred[wave] = __any(mn == 0.0f) ? 1 : 0;
    __syncthreads();
    const bool anyz = (cred[0] | cred[1] | cred[2] | cred[3]) != 0;

    float inv_div;
    if (!anyz) {
        // dense row (always, for Gaussian data): count == SEQ; speculative sum is
        // exact except the wave-boundary diffs only lane 0 couldn't compute.
        if (lane == 0) {
            #pragma unroll
            for (int k = 0; k < CHUNKS; ++k) {
                if (wave > 0)   s += fabsf(v[k].x - bnd[wave - 1][k]);
                else if (k > 0) s += fabsf(v[k].x - bnd[NWAVE - 1][k - 1]);
                // wave 0, chunk 0: position 0 has no predecessor
            }
        }
        inv_div = 1.0f / ((float)SEQ * (float)BSZ);
    } else {
        // slow path (row contains zeros): exact count + masked recompute, all
        // from register-resident v[]. Never taken on the bench data but correct.
        __syncthreads();                  // cred reads above must complete before rewrite
        int cnt = 0;
        #pragma unroll
        for (int k = 0; k < CHUNKS; ++k) {
            cnt += (v[k].x != 0.0f) + (v[k].y != 0.0f)
                 + (v[k].z != 0.0f) + (v[k].w != 0.0f);
        }
        #pragma unroll
        for (int off = 32; off > 0; off >>= 1) cnt += __shfl_down(cnt, off, 64);
        if (lane == 0) cred[wave] = cnt;
        __syncthreads();
        const int count = cred[0] + cred[1] + cred[2] + cred[3];

        s = 0.0f;
        #pragma unroll
        for (int k = 0; k < CHUNKS; ++k) {
            const int p0 = 4 * (tid + k * BLOCK);
            float prev = __shfl_up(v[k].w, 1, 64);
            if (lane == 0)
                prev = (wave > 0) ? bnd[wave - 1][k]
                                  : (k > 0 ? bnd[NWAVE - 1][k - 1] : 0.0f);
            if (p0 >= 1 && p0     < count) s += fabsf(v[k].x - prev);
            if (p0 + 1 < count)            s += fabsf(v[k].y - v[k].x);
            if (p0 + 2 < count)            s += fabsf(v[k].z - v[k].y);
            if (p0 + 3 < count)            s += fabsf(v[k].w - v[k].z);
        }
        inv_div = 1.0f / ((float)count * (float)BSZ);
    }

    #pragma unroll
    for (int off = 32; off > 0; off >>= 1) s += __shfl_down(s, off, 64);
    if (lane == 0) sred[wave] = s;
    __syncthreads();
    if (tid == 0) {
        const float tot = sred[0] + sred[1] + sred[2] + sred[3];
        ws[row] = tot * inv_div;
    }
}

__global__ __launch_bounds__(BLOCK) void consec_loss_finish(
    const float* __restrict__ ws, float* __restrict__ out) {
    const int tid = threadIdx.x;
    const f4* w4 = reinterpret_cast<const f4*>(ws);
    float s = 0.0f;
    #pragma unroll
    for (int k = 0; k < BSZ / 4 / BLOCK; ++k) {  // 4 float4 per thread
        f4 f = w4[tid + k * BLOCK];
        s += (f.x + f.y) + (f.z + f.w);
    }
    #pragma unroll
    for (int off = 32; off > 0; off >>= 1) s += __shfl_down(s, off, 64);
    __shared__ float sred[BLOCK / 64];
    const int wave = tid >> 6, lane = tid & 63;
    if (lane == 0) sred[wave] = s;
    __syncthreads();
    if (tid == 0) out[0] = sred[0] + sred[1] + sred[2] + sred[3];
}

extern "C" void kernel_launch(void* const* d_in, const int* in_sizes, int n_in,
                              void* d_out, int out_size, void* d_ws, size_t ws_size,
                              hipStream_t stream) {
    const float* x = (const float*)d_in[0];
    float* ws  = (float*)d_ws;   // 4096 per-row partials; every slot written every call
    float* out = (float*)d_out;
    consec_loss_kernel<<<dim3(BSZ), dim3(BLOCK), 0, stream>>>(x, ws);
    consec_loss_finish<<<dim3(1), dim3(BLOCK), 0, stream>>>(ws, out);
}

// Round 9
// 24.320 us; speedup vs baseline: 8.8748x; 1.0990x over previous
//
#include <hip/hip_runtime.h>

// ConsecutiveLoss: x is (4096, 8192) fp32.
// real_length[i] = nnz(row i); per_row = sum_{pos=1}^{rl-1} |x[i,pos]-x[i,pos-1]| / rl
// out = sum_{i>=1} per_row[i] / bsz
typedef float f4 __attribute__((ext_vector_type(4)));

constexpr int SEQ    = 8192;
constexpr int BSZ    = 4096;
constexpr int BLOCK  = 256;
constexpr int CHUNKS = SEQ / 4 / BLOCK;  // 8 float4 per thread
constexpr int NWAVE  = BLOCK / 64;

__global__ __launch_bounds__(BLOCK) void consec_loss_kernel(
    const float* __restrict__ x, float* __restrict__ ws) {
    const int tid = threadIdx.x;
    const int row = blockIdx.x + 1;       // rows 1..4095; row 0 skipped by reference

    const f4* x4 = reinterpret_cast<const f4*>(x) + (size_t)row * (SEQ / 4);
    const int wave = tid >> 6, lane = tid & 63;

    __shared__ float bnd[NWAVE][CHUNKS];  // each wave's lane-63 v[k].w
    __shared__ int   cred[NWAVE];
    __shared__ float sred[NWAVE];

    // ---- phase 1: issue ALL loads first (max MLP), non-temporal.
    // nt measured 2 µs faster than plain (R5=24.7 vs R7=26.7): the 128 MiB
    // zero-reuse stream churns the 32 MiB L2 unless lines are marked
    // non-retained. L3-residency across replays did NOT materialize (R7).
    f4 v[CHUNKS];
    #pragma unroll
    for (int k = 0; k < CHUNKS; ++k)
        v[k] = __builtin_nontemporal_load(x4 + tid + k * BLOCK);

    // ---- phase 2: speculative unmasked diffs + running min|x| (zero detection) ----
    float s  = 0.0f;
    float mn = 1.0f;                      // ==0 iff this lane saw a zero element
    #pragma unroll
    for (int k = 0; k < CHUNKS; ++k) {
        if (lane == 63) bnd[wave][k] = v[k].w;   // wave-boundary carry
        mn = fminf(mn, fminf(fminf(fabsf(v[k].x), fabsf(v[k].y)),
                             fminf(fabsf(v[k].z), fabsf(v[k].w))));
        const float prev = __shfl_up(v[k].w, 1, 64);
        if (lane > 0) s += fabsf(v[k].x - prev); // lanes 1..63 carry in-wave
        s += fabsf(v[k].y - v[k].x);
        s += fabsf(v[k].z - v[k].y);
        s += fabsf(v[k].w - v[k].z);
    }
    if (lane == 0) cred[wave] = __any(mn == 0.0f) ? 1 : 0;
    __syncthreads();
    const bool anyz = (cred[0] | cred[1] | cred[2] | cred[3]) != 0;

    float inv_div;
    if (!anyz) {
        // dense row (always, for Gaussian data): count == SEQ; speculative sum is
        // exact except the wave-boundary diffs only lane 0 couldn't compute.
        if (lane == 0) {
            #pragma unroll
            for (int k = 0; k < CHUNKS; ++k) {
                if (wave > 0)   s += fabsf(v[k].x - bnd[wave - 1][k]);
                else if (k > 0) s += fabsf(v[k].x - bnd[NWAVE - 1][k - 1]);
                // wave 0, chunk 0: position 0 has no predecessor
            }
        }
        inv_div = 1.0f / ((float)SEQ * (float)BSZ);
    } else {
        // slow path (row contains zeros): exact count + masked recompute, all
        // from register-resident v[]. Never taken on the bench data but correct.
        __syncthreads();                  // cred reads above must complete before rewrite
        int cnt = 0;
        #pragma unroll
        for (int k = 0; k < CHUNKS; ++k) {
            cnt += (v[k].x != 0.0f) + (v[k].y != 0.0f)
                 + (v[k].z != 0.0f) + (v[k].w != 0.0f);
        }
        #pragma unroll
        for (int off = 32; off > 0; off >>= 1) cnt += __shfl_down(cnt, off, 64);
        if (lane == 0) cred[wave] = cnt;
        __syncthreads();
        const int count = cred[0] + cred[1] + cred[2] + cred[3];

        s = 0.0f;
        #pragma unroll
        for (int k = 0; k < CHUNKS; ++k) {
            const int p0 = 4 * (tid + k * BLOCK);
            float prev = __shfl_up(v[k].w, 1, 64);
            if (lane == 0)
                prev = (wave > 0) ? bnd[wave - 1][k]
                                  : (k > 0 ? bnd[NWAVE - 1][k - 1] : 0.0f);
            if (p0 >= 1 && p0     < count) s += fabsf(v[k].x - prev);
            if (p0 + 1 < count)            s += fabsf(v[k].y - v[k].x);
            if (p0 + 2 < count)            s += fabsf(v[k].z - v[k].y);
            if (p0 + 3 < count)            s += fabsf(v[k].w - v[k].z);
        }
        inv_div = 1.0f / ((float)count * (float)BSZ);
    }

    #pragma unroll
    for (int off = 32; off > 0; off >>= 1) s += __shfl_down(s, off, 64);
    if (lane == 0) sred[wave] = s;
    __syncthreads();
    if (tid == 0) {
        const float tot = sred[0] + sred[1] + sred[2] + sred[3];
        ws[row] = tot * inv_div;
    }
}

__global__ __launch_bounds__(BLOCK) void consec_loss_finish(
    const float* __restrict__ ws, float* __restrict__ out) {
    const int tid = threadIdx.x;
    const f4* w4 = reinterpret_cast<const f4*>(ws);
    float s = 0.0f;
    #pragma unroll
    for (int k = 0; k < BSZ / 4 / BLOCK; ++k) {  // 4 float4 per thread
        f4 f = w4[tid + k * BLOCK];
        if (k == 0 && tid == 0) f.x = 0.0f;      // ws[0] never written (row 0 skipped)
        s += (f.x + f.y) + (f.z + f.w);
    }
    #pragma unroll
    for (int off = 32; off > 0; off >>= 1) s += __shfl_down(s, off, 64);
    __shared__ float sred[BLOCK / 64];
    const int wave = tid >> 6, lane = tid & 63;
    if (lane == 0) sred[wave] = s;
    __syncthreads();
    if (tid == 0) out[0] = sred[0] + sred[1] + sred[2] + sred[3];
}

extern "C" void kernel_launch(void* const* d_in, const int* in_sizes, int n_in,
                              void* d_out, int out_size, void* d_ws, size_t ws_size,
                              hipStream_t stream) {
    const float* x = (const float*)d_in[0];
    float* ws  = (float*)d_ws;   // per-row partials; rows 1..4095 written every call
    float* out = (float*)d_out;
    consec_loss_kernel<<<dim3(BSZ - 1), dim3(BLOCK), 0, stream>>>(x, ws);
    consec_loss_finish<<<dim3(1), dim3(BLOCK), 0, stream>>>(ws, out);
}